// Round 14
// baseline (115.944 us; speedup 1.0000x reference)
//
#include <hip/hip_runtime.h>

#define BS 8192
#define D  128
#define TI 64               // i-rows per block (ONE wave)
#define JCHUNK 512          // j's per block chunk
#define NJC (BS / JCHUNK)   // 16
#define NP 16               // panels per chunk (32 j-rows each)
#define NIB (BS / TI)       // 128 i-blocks

typedef __bf16 bf16x8 __attribute__((ext_vector_type(8)));
typedef float  f32x16 __attribute__((ext_vector_type(16)));

// ---------------------------------------------------------------------------
// pack v2: 512 blocks (2/CU) — 4x the parallelism of the old 256-block pack,
// which at 1 block/CU was likely the hidden ~10 us of the R8-R13 plateau.
// Thread <-> one 32-B fragment piece of BOTH A and P:
//   b = tile*2 + seg; r = seg*16 + (tid>>4); inner = tid&15
//   k-range = inner*8 .. +8  (16 consecutive tids read one 512-B row: coalesced)
//   piece index = (tile*8 + (inner>>1))*64 + (inner&1)*32 + r   [layout R6-R13]
// Row reductions via 16-lane shuffle groups. Block 0 zeroes tickets/accum.
// ---------------------------------------------------------------------------
__global__ __launch_bounds__(256) void pack_kernel(
        const float* __restrict__ feats,
        __bf16* __restrict__ Apack, __bf16* __restrict__ Ppack,
        float* __restrict__ a_sq, float* __restrict__ p_sq,
        float* __restrict__ pd2, float* __restrict__ accum,
        unsigned int* __restrict__ cnt, unsigned int* __restrict__ ticket)
{
    const int b   = blockIdx.x;           // 0..511
    const int tid = threadIdx.x;

    if (b == 0) {
        if (tid < NIB)            ticket[tid] = 0u;
        else if (tid == NIB)      *accum = 0.0f;
        else if (tid == NIB + 1)  *cnt = 0u;
    }

    const int tile  = b >> 1;
    const int seg   = b & 1;
    const int rl    = tid >> 4;           // 0..15
    const int inner = tid & 15;           // 0..15 piece-in-row
    const int r     = seg * 16 + rl;      // row in tile, 0..31
    const int row   = tile * 32 + r;
    const int s     = inner >> 1;
    const int half  = inner & 1;

    const float4* asrc = (const float4*)(feats + (size_t)row * D + inner * 8);
    const float4* psrc = (const float4*)(feats + (size_t)(row + BS) * D + inner * 8);
    float4 a0 = asrc[0], a1 = asrc[1];
    float4 p0 = psrc[0], p1 = psrc[1];

    bf16x8 ap, pp;
    ap[0]=(__bf16)a0.x; ap[1]=(__bf16)a0.y; ap[2]=(__bf16)a0.z; ap[3]=(__bf16)a0.w;
    ap[4]=(__bf16)a1.x; ap[5]=(__bf16)a1.y; ap[6]=(__bf16)a1.z; ap[7]=(__bf16)a1.w;
    pp[0]=(__bf16)p0.x; pp[1]=(__bf16)p0.y; pp[2]=(__bf16)p0.z; pp[3]=(__bf16)p0.w;
    pp[4]=(__bf16)p1.x; pp[5]=(__bf16)p1.y; pp[6]=(__bf16)p1.z; pp[7]=(__bf16)p1.w;

    const size_t pi = ((size_t)tile * 8 + s) * 64 + half * 32 + r;
    ((bf16x8*)Apack)[pi] = ap;
    ((bf16x8*)Ppack)[pi] = pp;

    float sa = a0.x*a0.x + a0.y*a0.y + a0.z*a0.z + a0.w*a0.w
             + a1.x*a1.x + a1.y*a1.y + a1.z*a1.z + a1.w*a1.w;
    float sp = p0.x*p0.x + p0.y*p0.y + p0.z*p0.z + p0.w*p0.w
             + p1.x*p1.x + p1.y*p1.y + p1.z*p1.z + p1.w*p1.w;
    float d, sd = 0.0f;
    d = a0.x-p0.x; sd += d*d;  d = a0.y-p0.y; sd += d*d;
    d = a0.z-p0.z; sd += d*d;  d = a0.w-p0.w; sd += d*d;
    d = a1.x-p1.x; sd += d*d;  d = a1.y-p1.y; sd += d*d;
    d = a1.z-p1.z; sd += d*d;  d = a1.w-p1.w; sd += d*d;

    // reduce across the 16 consecutive lanes of this row
    #pragma unroll
    for (int off = 1; off <= 8; off <<= 1) {
        sa += __shfl_xor(sa, off, 64);
        sp += __shfl_xor(sp, off, 64);
        sd += __shfl_xor(sd, off, 64);
    }
    if (inner == 0) { a_sq[row] = sa; p_sq[row] = sp; pd2[row] = sd; }
}

// ---------------------------------------------------------------------------
// max kernel: ONE-WAVE blocks (64 thr), 64 i-rows x 512 j-chunk; grid
// (128,16) = 2048 blocks -> 8 INDEPENDENT waves/CU with decorrelated stall
// schedules (R12's 2-wave blocks stalled in lockstep on shared B loads).
// Registers-only B pipeline (R12, best measured): B panels (32 j-rows)
// double-buffer in registers, panel t+1's 8 coalesced 1 KB loads issue
// before panel t's MFMAs, exact per-register vmcnt tracking, no LDS, no
// barriers. ~240 VGPR fits (64,2)'s 256 budget, no spill.
//
// acc initialized to -p_sq[col]/2, so after the K-loop acc = cross - p_sq/2
// and min_j d2 = a_sq - 2*max acc -> one v_max per reg.
//
// Fused finish: per-i-block ticket; the 16th contributor computes the loss
// terms for its 64 rows and atomically accumulates; the 128th finisher
// writes out. (Pattern proven correct in R13.)
//
// mfma_f32_32x32x16_bf16 C/D layout (HW-verified, learn_hip m74/m101):
//   col = lane&31, row = (reg&3) + 8*(reg>>2) + 4*(lane>>5)
// ---------------------------------------------------------------------------
__global__ __launch_bounds__(64, 2) void max_kernel(
        const __bf16* __restrict__ Apack, const __bf16* __restrict__ Ppack,
        const float* __restrict__ p_sq, const float* __restrict__ a_sq,
        const float* __restrict__ pd2, float* __restrict__ partmax,
        float* __restrict__ accum, unsigned int* __restrict__ cnt,
        unsigned int* __restrict__ ticket, float* __restrict__ out)
{
    const int lane = threadIdx.x;               // 0..63 (one wave)
    const int l31  = lane & 31;
    const int half = lane >> 5;

    const int ib    = blockIdx.x;               // i-block, 0..127
    const int jc    = blockIdx.y;               // j-chunk, 0..15
    const int i0    = ib * TI;
    const int itile = i0 >> 5;
    const int jbase = jc * JCHUNK;
    const int tile0 = jbase >> 5;

    // A fragments (2 tiles), coalesced 1 KB wave-loads from Apack
    bf16x8 afA[8], afB[8];
    {
        const bf16x8* ap = (const bf16x8*)Apack;
        #pragma unroll
        for (int s = 0; s < 8; ++s) {
            afA[s] = ap[((size_t)itile * 8 + s) * 64 + lane];
            afB[s] = ap[((size_t)(itile + 1) * 8 + s) * 64 + lane];
        }
    }

    float rmaxA[16], rmaxB[16];
    #pragma unroll
    for (int r = 0; r < 16; ++r) { rmaxA[r] = -3.0e38f; rmaxB[r] = -3.0e38f; }

    // panel piece stream: panel p = pieces gp[p*512 + s*64], lane-offset
    const bf16x8* gp = (const bf16x8*)Ppack + (size_t)tile0 * 512 + lane;

    // register double buffer: prologue loads panel 0
    bf16x8 bcur[8], bnxt[8];
    #pragma unroll
    for (int s = 0; s < 8; ++s) bcur[s] = gp[s * 64];
    float cicur = -0.5f * p_sq[jbase + l31];
    float cinxt = 0.0f;

    #pragma unroll 2
    for (int t = 0; t < NP; ++t) {
        if (t + 1 < NP) {
            #pragma unroll
            for (int s = 0; s < 8; ++s) bnxt[s] = gp[(t + 1) * 512 + s * 64];
            cinxt = -0.5f * p_sq[jbase + (t + 1) * 32 + l31];
        }

        f32x16 acc0, acc1;
        #pragma unroll
        for (int r = 0; r < 16; ++r) { acc0[r] = cicur; acc1[r] = cicur; }
        #pragma unroll
        for (int s = 0; s < 8; ++s) {
            acc0 = __builtin_amdgcn_mfma_f32_32x32x16_bf16(afA[s], bcur[s],
                                                           acc0, 0, 0, 0);
            acc1 = __builtin_amdgcn_mfma_f32_32x32x16_bf16(afB[s], bcur[s],
                                                           acc1, 0, 0, 0);
        }
        #pragma unroll
        for (int r = 0; r < 16; ++r) {
            rmaxA[r] = fmaxf(rmaxA[r], acc0[r]);
            rmaxB[r] = fmaxf(rmaxB[r], acc1[r]);
        }

        if (t + 1 < NP) {
            #pragma unroll
            for (int s = 0; s < 8; ++s) bcur[s] = bnxt[s];  // renamed by unroll-2
            cicur = cinxt;
        }
    }

    // max across the 32 columns (lanes sharing the same half)
    #pragma unroll
    for (int r = 0; r < 16; ++r) {
        float vA = rmaxA[r], vB = rmaxB[r];
        #pragma unroll
        for (int off = 1; off <= 16; off <<= 1) {
            vA = fmaxf(vA, __shfl_xor(vA, off, 64));
            vB = fmaxf(vB, __shfl_xor(vB, off, 64));
        }
        rmaxA[r] = vA; rmaxB[r] = vB;
    }
    if (l31 == 0) {
        float* dst = partmax + (size_t)jc * BS + i0;
        #pragma unroll
        for (int r = 0; r < 16; ++r) {
            int row = (r & 3) + 8 * (r >> 2) + 4 * half;
            dst[row]      = rmaxA[r];
            dst[row + 32] = rmaxB[r];
        }
    }

    // ---- fused finish (release/acquire via device-scope atomics) ----
    __threadfence();
    unsigned int old = 0u;
    if (lane == 0) old = atomicAdd(&ticket[ib], 1u);
    old = __shfl(old, 0, 64);
    if (old == NJC - 1) {
        __threadfence();
        const int i = i0 + lane;
        float m = -3.0e38f;
        #pragma unroll
        for (int c = 0; c < NJC; ++c)
            m = fmaxf(m, partmax[c * BS + i]);
        float negd = sqrtf(fmaxf(fmaf(-2.0f, m, a_sq[i]), 0.0f));
        float posd = sqrtf(pd2[i]);
        float v = fmaxf(posd - negd + 1.0f, 0.0f);
        #pragma unroll
        for (int off = 32; off >= 1; off >>= 1) v += __shfl_xor(v, off, 64);
        if (lane == 0) {
            atomicAdd(accum, v);
            __threadfence();
            unsigned int o2 = atomicAdd(cnt, 1u);
            if (o2 == NIB - 1)
                out[0] = atomicAdd(accum, 0.0f) * (1.0f / (float)BS);
        }
    }
}

// ---------------------------------------------------------------------------
extern "C" void kernel_launch(void* const* d_in, const int* in_sizes, int n_in,
                              void* d_out, int out_size, void* d_ws,
                              size_t ws_size, hipStream_t stream)
{
    const float* feats = (const float*)d_in[0];

    char* ws = (char*)d_ws;
    __bf16* Apack = (__bf16*)ws;  ws += (size_t)BS * D * 2;   // 2 MB
    __bf16* Ppack = (__bf16*)ws;  ws += (size_t)BS * D * 2;   // 2 MB
    float* a_sq   = (float*)ws;   ws += (size_t)BS * 4;
    float* p_sq   = (float*)ws;   ws += (size_t)BS * 4;
    float* pd2    = (float*)ws;   ws += (size_t)BS * 4;
    float* partmax = (float*)ws;  ws += (size_t)NJC * BS * 4; // 512 KB
    float* accum  = (float*)ws;   ws += 64;
    unsigned int* cnt = (unsigned int*)ws;    ws += 64;
    unsigned int* ticket = (unsigned int*)ws; ws += NIB * 4;

    pack_kernel<<<512, 256, 0, stream>>>(feats, Apack, Ppack,
                                         a_sq, p_sq, pd2, accum, cnt, ticket);
    dim3 grid(NIB, NJC);
    max_kernel<<<grid, 64, 0, stream>>>(Apack, Ppack, p_sq, a_sq, pd2,
                                        partmax, accum, cnt, ticket,
                                        (float*)d_out);
}

// Round 15
// 82.222 us; speedup vs baseline: 1.4101x; 1.4101x over previous
//
#include <hip/hip_runtime.h>

#define BS 8192
#define D  128
#define TI 128              // i-rows per block (2 waves x 64)
#define JCHUNK 512          // j's per block chunk
#define NJC (BS / JCHUNK)   // 16
#define NP 16               // panels per chunk (32 j-rows each)
#define NIB (BS / TI)       // 64 i-blocks

typedef __bf16 bf16x8 __attribute__((ext_vector_type(8)));
typedef float  f32x16 __attribute__((ext_vector_type(16)));

// ---------------------------------------------------------------------------
// pack v2: 512 blocks (2/CU), fully coalesced. Thread <-> one 32-B fragment
// piece of BOTH A and P:
//   b = tile*2 + seg; r = seg*16 + (tid>>4); inner = tid&15
//   k-range = inner*8 .. +8  (16 consecutive tids read one 512-B row)
//   piece index = (tile*8 + (inner>>1))*64 + (inner&1)*32 + r  [layout R6-R14]
// Row reductions via 16-lane shuffle groups.
// ---------------------------------------------------------------------------
__global__ __launch_bounds__(256) void pack_kernel(
        const float* __restrict__ feats,
        __bf16* __restrict__ Apack, __bf16* __restrict__ Ppack,
        float* __restrict__ a_sq, float* __restrict__ p_sq,
        float* __restrict__ pd2)
{
    const int b   = blockIdx.x;           // 0..511
    const int tid = threadIdx.x;

    const int tile  = b >> 1;
    const int seg   = b & 1;
    const int rl    = tid >> 4;           // 0..15
    const int inner = tid & 15;           // 0..15 piece-in-row
    const int r     = seg * 16 + rl;      // row in tile, 0..31
    const int row   = tile * 32 + r;
    const int s     = inner >> 1;
    const int half  = inner & 1;

    const float4* asrc = (const float4*)(feats + (size_t)row * D + inner * 8);
    const float4* psrc = (const float4*)(feats + (size_t)(row + BS) * D + inner * 8);
    float4 a0 = asrc[0], a1 = asrc[1];
    float4 p0 = psrc[0], p1 = psrc[1];

    bf16x8 ap, pp;
    ap[0]=(__bf16)a0.x; ap[1]=(__bf16)a0.y; ap[2]=(__bf16)a0.z; ap[3]=(__bf16)a0.w;
    ap[4]=(__bf16)a1.x; ap[5]=(__bf16)a1.y; ap[6]=(__bf16)a1.z; ap[7]=(__bf16)a1.w;
    pp[0]=(__bf16)p0.x; pp[1]=(__bf16)p0.y; pp[2]=(__bf16)p0.z; pp[3]=(__bf16)p0.w;
    pp[4]=(__bf16)p1.x; pp[5]=(__bf16)p1.y; pp[6]=(__bf16)p1.z; pp[7]=(__bf16)p1.w;

    const size_t pi = ((size_t)tile * 8 + s) * 64 + half * 32 + r;
    ((bf16x8*)Apack)[pi] = ap;
    ((bf16x8*)Ppack)[pi] = pp;

    float sa = a0.x*a0.x + a0.y*a0.y + a0.z*a0.z + a0.w*a0.w
             + a1.x*a1.x + a1.y*a1.y + a1.z*a1.z + a1.w*a1.w;
    float sp = p0.x*p0.x + p0.y*p0.y + p0.z*p0.z + p0.w*p0.w
             + p1.x*p1.x + p1.y*p1.y + p1.z*p1.z + p1.w*p1.w;
    float d, sd = 0.0f;
    d = a0.x-p0.x; sd += d*d;  d = a0.y-p0.y; sd += d*d;
    d = a0.z-p0.z; sd += d*d;  d = a0.w-p0.w; sd += d*d;
    d = a1.x-p1.x; sd += d*d;  d = a1.y-p1.y; sd += d*d;
    d = a1.z-p1.z; sd += d*d;  d = a1.w-p1.w; sd += d*d;

    #pragma unroll
    for (int off = 1; off <= 8; off <<= 1) {
        sa += __shfl_xor(sa, off, 64);
        sp += __shfl_xor(sp, off, 64);
        sd += __shfl_xor(sd, off, 64);
    }
    if (inner == 0) { a_sq[row] = sa; p_sq[row] = sp; pd2[row] = sd; }
}

// ---------------------------------------------------------------------------
// max kernel — EXACT R12 best (82.0 us total): NO LDS, NO BARRIERS,
// registers-only B pipeline. 2-wave blocks (128 thr), 128 i-rows x 512
// j-chunk; each wave owns 64 rows (two A-fragment sets register-resident).
// B panels (32 j-rows) double-buffer in registers: panel t+1's 8 coalesced
// 1 KB loads issue before panel t's MFMAs (exact per-register vmcnt).
// The two waves read the SAME B addresses -> second wave hits L1 (R14's
// 1-wave variant, which lost this sharing, measured 62.6 us vs ~25: keep
// 2-wave blocks). Full unroll, launch_bounds(128,2), grid (64,16).
//
// acc initialized to -p_sq[col]/2, so after the K-loop acc = cross - p_sq/2
// and min_j d2 = a_sq - 2*max acc -> one v_max per reg.
//
// mfma_f32_32x32x16_bf16 C/D layout (HW-verified, learn_hip m74/m101):
//   col = lane&31, row = (reg&3) + 8*(reg>>2) + 4*(lane>>5)
// ---------------------------------------------------------------------------
__global__ __launch_bounds__(128, 2) void max_kernel(
        const __bf16* __restrict__ Apack, const __bf16* __restrict__ Ppack,
        const float* __restrict__ p_sq, float* __restrict__ partmax)
{
    const int tid  = threadIdx.x;               // 0..127
    const int wave = tid >> 6;                  // 0 or 1
    const int lane = tid & 63;
    const int l31  = lane & 31;
    const int half = lane >> 5;

    const int i0    = blockIdx.x * TI + wave * 64;    // wave's 64 anchor rows
    const int itile = i0 >> 5;
    const int jbase = blockIdx.y * JCHUNK;
    const int tile0 = jbase >> 5;

    // A fragments (2 tiles), coalesced 1 KB wave-loads from Apack
    bf16x8 afA[8], afB[8];
    {
        const bf16x8* ap = (const bf16x8*)Apack;
        #pragma unroll
        for (int s = 0; s < 8; ++s) {
            afA[s] = ap[((size_t)itile * 8 + s) * 64 + lane];
            afB[s] = ap[((size_t)(itile + 1) * 8 + s) * 64 + lane];
        }
    }

    float rmaxA[16], rmaxB[16];
    #pragma unroll
    for (int r = 0; r < 16; ++r) { rmaxA[r] = -3.0e38f; rmaxB[r] = -3.0e38f; }

    // panel piece stream: panel p = pieces gp[p*512 + s*64], lane-offset
    const bf16x8* gp = (const bf16x8*)Ppack + (size_t)tile0 * 512 + lane;

    // register double buffer: prologue loads panel 0
    bf16x8 bcur[8], bnxt[8];
    #pragma unroll
    for (int s = 0; s < 8; ++s) bcur[s] = gp[s * 64];
    float cicur = -0.5f * p_sq[jbase + l31];
    float cinxt = 0.0f;

    #pragma unroll
    for (int t = 0; t < NP; ++t) {
        if (t + 1 < NP) {
            // prefetch panel t+1 into registers (stays in flight across
            // panel t's MFMAs; exact vmcnt tracking, no drain)
            #pragma unroll
            for (int s = 0; s < 8; ++s) bnxt[s] = gp[(t + 1) * 512 + s * 64];
            cinxt = -0.5f * p_sq[jbase + (t + 1) * 32 + l31];
        }

        f32x16 acc0, acc1;
        #pragma unroll
        for (int r = 0; r < 16; ++r) { acc0[r] = cicur; acc1[r] = cicur; }
        #pragma unroll
        for (int s = 0; s < 8; ++s) {
            acc0 = __builtin_amdgcn_mfma_f32_32x32x16_bf16(afA[s], bcur[s],
                                                           acc0, 0, 0, 0);
            acc1 = __builtin_amdgcn_mfma_f32_32x32x16_bf16(afB[s], bcur[s],
                                                           acc1, 0, 0, 0);
        }
        #pragma unroll
        for (int r = 0; r < 16; ++r) {
            rmaxA[r] = fmaxf(rmaxA[r], acc0[r]);
            rmaxB[r] = fmaxf(rmaxB[r], acc1[r]);
        }

        if (t + 1 < NP) {
            #pragma unroll
            for (int s = 0; s < 8; ++s) bcur[s] = bnxt[s];  // renamed away
            cicur = cinxt;
        }
    }

    // max across the 32 columns (lanes sharing the same half)
    #pragma unroll
    for (int r = 0; r < 16; ++r) {
        float vA = rmaxA[r], vB = rmaxB[r];
        #pragma unroll
        for (int off = 1; off <= 16; off <<= 1) {
            vA = fmaxf(vA, __shfl_xor(vA, off, 64));
            vB = fmaxf(vB, __shfl_xor(vB, off, 64));
        }
        rmaxA[r] = vA; rmaxB[r] = vB;
    }
    if (l31 == 0) {
        float* dst = partmax + (size_t)blockIdx.y * BS + i0;
        #pragma unroll
        for (int r = 0; r < 16; ++r) {
            int row = (r & 3) + 8 * (r >> 2) + 4 * half;
            dst[row]      = rmaxA[r];
            dst[row + 32] = rmaxB[r];
        }
    }
}

// ---------------------------------------------------------------------------
// fin stage 1: 32 blocks x 256 threads; thread handles exactly one i.
// min_j d2 = a_sq[i] - 2 * max_c partmax[c][i]
// ---------------------------------------------------------------------------
__global__ __launch_bounds__(256) void fin1_kernel(
        const float* __restrict__ partmax, const float* __restrict__ a_sq,
        const float* __restrict__ pd2, float* __restrict__ bsum)
{
    __shared__ float ssum[4];
    const int t = threadIdx.x;
    const int i = blockIdx.x * 256 + t;

    float m = -3.0e38f;
    #pragma unroll
    for (int c = 0; c < NJC; ++c)
        m = fmaxf(m, partmax[c * BS + i]);
    float negd = sqrtf(fmaxf(fmaf(-2.0f, m, a_sq[i]), 0.0f));
    float posd = sqrtf(pd2[i]);
    float sum = fmaxf(posd - negd + 1.0f, 0.0f);

    #pragma unroll
    for (int off = 32; off >= 1; off >>= 1) sum += __shfl_xor(sum, off, 64);
    if ((t & 63) == 0) ssum[t >> 6] = sum;
    __syncthreads();
    if (t == 0)
        bsum[blockIdx.x] = ssum[0] + ssum[1] + ssum[2] + ssum[3];
}

// fin stage 2: one wave sums the 32 block partials.
__global__ __launch_bounds__(64) void fin2_kernel(
        const float* __restrict__ bsum, float* __restrict__ out)
{
    const int t = threadIdx.x;
    float v = (t < 32) ? bsum[t] : 0.0f;
    #pragma unroll
    for (int off = 32; off >= 1; off >>= 1) v += __shfl_xor(v, off, 64);
    if (t == 0) out[0] = v / (float)BS;
}

// ---------------------------------------------------------------------------
extern "C" void kernel_launch(void* const* d_in, const int* in_sizes, int n_in,
                              void* d_out, int out_size, void* d_ws,
                              size_t ws_size, hipStream_t stream)
{
    const float* feats = (const float*)d_in[0];

    char* ws = (char*)d_ws;
    __bf16* Apack = (__bf16*)ws;  ws += (size_t)BS * D * 2;   // 2 MB
    __bf16* Ppack = (__bf16*)ws;  ws += (size_t)BS * D * 2;   // 2 MB
    float* a_sq   = (float*)ws;   ws += (size_t)BS * 4;
    float* p_sq   = (float*)ws;   ws += (size_t)BS * 4;
    float* pd2    = (float*)ws;   ws += (size_t)BS * 4;
    float* partmax = (float*)ws;  ws += (size_t)NJC * BS * 4; // 512 KB
    float* bsum   = (float*)ws;   ws += 32 * 4;

    pack_kernel<<<512, 256, 0, stream>>>(feats, Apack, Ppack,
                                         a_sq, p_sq, pd2);
    dim3 grid(NIB, NJC);
    max_kernel<<<grid, 128, 0, stream>>>(Apack, Ppack, p_sq, partmax);
    fin1_kernel<<<BS / 256, 256, 0, stream>>>(partmax, a_sq, pd2, bsum);
    fin2_kernel<<<1, 64, 0, stream>>>(bsum, (float*)d_out);
}